// Round 7
// baseline (88.944 us; speedup 1.0000x reference)
//
#include <hip/hip_runtime.h>
#include <hip/hip_bf16.h>
#include <cstdint>
#include <cstddef>

// BesselKANLayer: y[b,o] = sum_{i,d} bessel_d(tanh(x[b,i])) * C[i,o,d]
// b0 == 1 folded into bias; GEMM K = 3*1024.
// GEMM: BM=256 BN=128 BK=64, 256 thr (4 waves 2Mx2N, wave tile 128x64 ->
// 0.375 ds_read/MFMA). SINGLE frag set (~250 VGPR, no spill — rounds 5/6
// failed on frag double-buffer spill). NO manual lgkm fences: compiler's
// fine-grained lgkmcnt interleaves MFMA with read drain (m97 mechanism).
// Triple-buffered LDS, stage distance 2, counted vmcnt(12), XOR swizzle.

#define BATCH   8192
#define IN_DIM  1024
#define OUT_DIM 1024
#define KDIM    3072
#define NT      48            // KDIM/64 K-tiles
#define BM      256
#define BN      128
#define LDS_TILE 24576        // shorts per buffer: A 256*64=16384 + B 128*64=8192

typedef __attribute__((ext_vector_type(4))) float f32x4;
typedef __attribute__((ext_vector_type(8))) short bf16x8;

static __device__ __forceinline__ short f2bf(float f) {
    uint32_t u = __float_as_uint(f);
    u += 0x7fffu + ((u >> 16) & 1u);
    return (short)(u >> 16);
}

// ---------------- prep: basis matrix A [8192][3072] bf16 ----------------
__global__ __launch_bounds__(256) void prep_basis(const float* __restrict__ x,
                                                  short* __restrict__ A) {
    int idx = blockIdx.x * 256 + threadIdx.x;
    int b = idx >> 8;
    int i = (idx & 255) << 2;
    const float4 xv = *reinterpret_cast<const float4*>(&x[(size_t)b * IN_DIM + i]);
    float xs[4] = {xv.x, xv.y, xv.z, xv.w};
    short o1[4], o2[4], o3[4];
#pragma unroll
    for (int j = 0; j < 4; ++j) {
        float t  = tanhf(xs[j]);
        float b1 = t + 1.0f;
        float b2 = 3.0f * t * b1 + 1.0f;
        float b3 = 5.0f * t * b2 + b1;
        o1[j] = f2bf(b1); o2[j] = f2bf(b2); o3[j] = f2bf(b3);
    }
    short* row = A + (size_t)b * KDIM;
    *reinterpret_cast<short4*>(&row[i])              = make_short4(o1[0], o1[1], o1[2], o1[3]);
    *reinterpret_cast<short4*>(&row[IN_DIM + i])     = make_short4(o2[0], o2[1], o2[2], o2[3]);
    *reinterpret_cast<short4*>(&row[2 * IN_DIM + i]) = make_short4(o3[0], o3[1], o3[2], o3[3]);
}

// -------- prep: Bt [1024][3072] bf16 transpose + bias[o] = sum_i C[i][o][0] --------
__global__ __launch_bounds__(256) void prep_coeffs(const float* __restrict__ C,
                                                   short* __restrict__ Bt,
                                                   float* __restrict__ bias) {
    __shared__ short tile[3][32][33];
    __shared__ float red[8][32];
    const int i0 = blockIdx.x * 32;
    const int o0 = blockIdx.y * 32;
    const int t  = threadIdx.x;
    const int lo = t & 31;
    const int li = t >> 5;   // 0..7
    float part = 0.0f;
#pragma unroll
    for (int r = 0; r < 4; ++r) {
        int i = li + r * 8;
        const float4 c4 = *reinterpret_cast<const float4*>(
            &C[((size_t)(i0 + i) * OUT_DIM + (o0 + lo)) * 4]);
        tile[0][i][lo] = f2bf(c4.y);
        tile[1][i][lo] = f2bf(c4.z);
        tile[2][i][lo] = f2bf(c4.w);
        part += c4.x;
    }
    red[li][lo] = part;
    __syncthreads();
#pragma unroll
    for (int r = 0; r < 4; ++r) {
        int o = (t >> 5) + r * 8;
        int i = t & 31;
#pragma unroll
        for (int d = 0; d < 3; ++d)
            Bt[(size_t)(o0 + o) * KDIM + d * IN_DIM + (i0 + i)] = tile[d][i][o];
    }
    if (t < 32) {
        float s = 0.0f;
#pragma unroll
        for (int k = 0; k < 8; ++k) s += red[k][t];
        atomicAdd(&bias[o0 + t], s);
    }
}

// ---------------- GEMM: out = A * Bt^T + bias ----------------
__global__ __launch_bounds__(256, 1) void gemm_kan(
    const short* __restrict__ A,     // [BATCH][KDIM]
    const short* __restrict__ Bt,    // [OUT_DIM][KDIM]
    const float* __restrict__ bias,  // [OUT_DIM]
    float* __restrict__ out)         // [BATCH][OUT_DIM]
{
    extern __shared__ short lds[];   // 3 * LDS_TILE shorts = 144 KB

    const int tid  = threadIdx.x;
    const int lane = tid & 63;
    const int wid  = tid >> 6;   // 0..3
    const int wm   = wid >> 1;   // 0..1 (M), wave tile 128 rows
    const int wn   = wid & 1;    // 0..1 (N), wave tile 64 cols

    // XCD-aware swizzle (round-2 proven): XCD k -> 4 brow x 8 bcol
    const int bid  = blockIdx.x;          // 0..255
    const int swz  = (bid & 7) * 32 + (bid >> 3);
    const int brow = (swz >> 3) * BM;
    const int bcol = (swz & 7) * BN;

    const int l15 = lane & 15, lh = lane >> 4, l7 = lane & 7;
    const int pc0 = lh ^ l7;            // phys chunk for kk=0 (swizzled)

    // lean fragment addressing: 4 base offsets + compile-time ds offsets
    // abase(kk=1) = abase ^ 32  (pc^4 -> *8 flips bit 5; row bits >= 64 safe)
    const int abase = (wm * 128 + l15) * 64 + pc0 * 8;
    const int bbase = 16384 + (wn * 64 + l15) * 64 + pc0 * 8;

    // staging geometry: 256 thr x 16B = 4 KB/instr = 32 rows; 12 instr/tile
    const int srow   = tid >> 3;                    // 0..31
    const int schunk = (tid & 7) ^ (srow & 7);      // inverse-swizzled src chunk

#define STAGE(KT_TILE, B)                                                             \
    do {                                                                              \
        const int kt_ = (KT_TILE) * 64;                                               \
        short* lbase_ = lds + (B) * LDS_TILE;                                         \
        _Pragma("unroll")                                                             \
        for (int s_ = 0; s_ < 8; ++s_) {                                              \
            __builtin_amdgcn_global_load_lds(                                         \
                (const __attribute__((address_space(1))) void*)(                      \
                    A + (size_t)(brow + s_ * 32 + srow) * KDIM + kt_ + schunk * 8),   \
                (__attribute__((address_space(3))) void*)(                            \
                    lbase_ + s_ * 2048 + tid * 8), 16, 0, 0);                         \
        }                                                                             \
        _Pragma("unroll")                                                             \
        for (int s_ = 0; s_ < 4; ++s_) {                                              \
            __builtin_amdgcn_global_load_lds(                                         \
                (const __attribute__((address_space(1))) void*)(                      \
                    Bt + (size_t)(bcol + s_ * 32 + srow) * KDIM + kt_ + schunk * 8),  \
                (__attribute__((address_space(3))) void*)(                            \
                    lbase_ + 16384 + s_ * 2048 + tid * 8), 16, 0, 0);                 \
        }                                                                             \
    } while (0)

// body T: stage(T+2) | read frags(T) | 64 MFMA (compiler-interleaved with
// read drain via its own fine-grained lgkmcnt) | counted vmcnt | barrier
#define BODY(T, RBUF, WBUF)                                                           \
    do {                                                                              \
        if ((T) + 2 < NT) STAGE((T) + 2, WBUF);                                       \
        const short* pa0_ = lds + (RBUF) * LDS_TILE + abase;                          \
        const short* pa1_ = lds + (RBUF) * LDS_TILE + (abase ^ 32);                   \
        const short* pb0_ = lds + (RBUF) * LDS_TILE + bbase;                          \
        const short* pb1_ = lds + (RBUF) * LDS_TILE + (bbase ^ 32);                   \
        bf16x8 af[8][2], bfr[4][2];                                                   \
        _Pragma("unroll")                                                             \
        for (int mi = 0; mi < 8; ++mi) {                                              \
            af[mi][0] = *reinterpret_cast<const bf16x8*>(pa0_ + mi * 1024);           \
            af[mi][1] = *reinterpret_cast<const bf16x8*>(pa1_ + mi * 1024);           \
        }                                                                             \
        _Pragma("unroll")                                                             \
        for (int ni = 0; ni < 4; ++ni) {                                              \
            bfr[ni][0] = *reinterpret_cast<const bf16x8*>(pb0_ + ni * 1024);          \
            bfr[ni][1] = *reinterpret_cast<const bf16x8*>(pb1_ + ni * 1024);          \
        }                                                                             \
        _Pragma("unroll")                                                             \
        for (int kk = 0; kk < 2; ++kk)                                                \
            _Pragma("unroll")                                                         \
            for (int mi = 0; mi < 8; ++mi)                                            \
                _Pragma("unroll")                                                     \
                for (int ni = 0; ni < 4; ++ni)                                        \
                    acc[mi][ni] = __builtin_amdgcn_mfma_f32_16x16x32_bf16(            \
                        af[mi][kk], bfr[ni][kk], acc[mi][ni], 0, 0, 0);               \
        if ((T) + 2 < NT) { asm volatile("s_waitcnt vmcnt(12)" ::: "memory"); }       \
        else              { asm volatile("s_waitcnt vmcnt(0)"  ::: "memory"); }       \
        __builtin_amdgcn_s_barrier();                                                 \
    } while (0)

    // prologue
    f32x4 acc[8][4];
#pragma unroll
    for (int ni = 0; ni < 4; ++ni) {
        float bv = bias[bcol + wn * 64 + ni * 16 + l15];
#pragma unroll
        for (int mi = 0; mi < 8; ++mi)
            acc[mi][ni] = (f32x4){bv, bv, bv, bv};
    }
    STAGE(0, 0);
    STAGE(1, 1);
    asm volatile("s_waitcnt vmcnt(12)" ::: "memory");  // tile 0 landed
    __builtin_amdgcn_s_barrier();

    // 48 bodies, buffer ring period 3: read T%3, write (T+2)%3
    for (int tt = 0; tt < NT; tt += 3) {
        BODY(tt + 0, 0, 2);
        BODY(tt + 1, 1, 0);
        BODY(tt + 2, 2, 1);
    }
#undef BODY
#undef STAGE

    // epilogue: C/D layout col = lane&15, row = (lane>>4)*4 + reg
#pragma unroll
    for (int mi = 0; mi < 8; ++mi) {
#pragma unroll
        for (int r = 0; r < 4; ++r) {
            int row = brow + wm * 128 + mi * 16 + (lane >> 4) * 4 + r;
            float* orow = out + (size_t)row * OUT_DIM + bcol + wn * 64 + l15;
#pragma unroll
            for (int ni = 0; ni < 4; ++ni)
                orow[ni * 16] = acc[mi][ni][r];
        }
    }
}

extern "C" void kernel_launch(void* const* d_in, const int* in_sizes, int n_in,
                              void* d_out, int out_size, void* d_ws, size_t ws_size,
                              hipStream_t stream) {
    (void)in_sizes; (void)n_in; (void)out_size; (void)ws_size;
    const float* x      = (const float*)d_in[0];
    const float* coeffs = (const float*)d_in[1];
    float* out = (float*)d_out;

    char* ws = (char*)d_ws;
    short* A    = (short*)ws;                                        // 48 MB
    short* Bt   = (short*)(ws + (size_t)BATCH * KDIM * 2);           // 6 MB
    float* bias = (float*)(ws + (size_t)BATCH * KDIM * 2
                              + (size_t)OUT_DIM * KDIM * 2);         // 4 KB

    hipFuncSetAttribute((const void*)gemm_kan,
                        hipFuncAttributeMaxDynamicSharedMemorySize,
                        3 * LDS_TILE * (int)sizeof(short));

    hipMemsetAsync(bias, 0, OUT_DIM * sizeof(float), stream);
    hipLaunchKernelGGL(prep_basis, dim3(BATCH * IN_DIM / 4 / 256), dim3(256), 0, stream,
                       x, A);
    hipLaunchKernelGGL(prep_coeffs, dim3(IN_DIM / 32, OUT_DIM / 32), dim3(256), 0, stream,
                       coeffs, Bt, bias);
    hipLaunchKernelGGL(gemm_kan, dim3((BATCH / BM) * (OUT_DIM / BN)), dim3(256),
                       3 * LDS_TILE * sizeof(short), stream,
                       A, Bt, bias, out);
}

// Round 8
// 81.994 us; speedup vs baseline: 1.0848x; 1.0848x over previous
//
#include <hip/hip_runtime.h>
#include <hip/hip_bf16.h>
#include <cstdint>
#include <cstddef>

// BesselKANLayer: y[b,o] = sum_{i,d} bessel_d(tanh(x[b,i])) * C[i,o,d]
// b0 == 1 folded into bias; GEMM K = 3*1024.
// GEMM: BM=256 BN=128 BK=64, 512 thr (8 waves 4Mx2N, per-wave 64x64).
// 8-phase-per-2-K-tiles schedule (HK template, m196/m198/m218b): each phase
// {ds_read 6-or-2 frag b128 | stage 3-DMA half | bar | lgkm0+SB0 | prio1 |
// 8 MFMA | prio0 | bar}; vmcnt(6) once per tile at last phase (never 0).
// Ring-3 LDS (144KB) so staging never collides with live reads.

#define BATCH   8192
#define IN_DIM  1024
#define OUT_DIM 1024
#define KDIM    3072
#define NT      48            // KDIM/64 K-tiles
#define BM      256
#define BN      128
#define LDS_TILE 24576        // shorts per buffer: A 256*64=16384 + B 128*64=8192

typedef __attribute__((ext_vector_type(4))) float f32x4;
typedef __attribute__((ext_vector_type(8))) short bf16x8;

static __device__ __forceinline__ short f2bf(float f) {
    uint32_t u = __float_as_uint(f);
    u += 0x7fffu + ((u >> 16) & 1u);
    return (short)(u >> 16);
}

// ---------------- prep: basis matrix A [8192][3072] bf16 ----------------
__global__ __launch_bounds__(256) void prep_basis(const float* __restrict__ x,
                                                  short* __restrict__ A) {
    int idx = blockIdx.x * 256 + threadIdx.x;
    int b = idx >> 8;
    int i = (idx & 255) << 2;
    const float4 xv = *reinterpret_cast<const float4*>(&x[(size_t)b * IN_DIM + i]);
    float xs[4] = {xv.x, xv.y, xv.z, xv.w};
    short o1[4], o2[4], o3[4];
#pragma unroll
    for (int j = 0; j < 4; ++j) {
        float t  = tanhf(xs[j]);
        float b1 = t + 1.0f;
        float b2 = 3.0f * t * b1 + 1.0f;
        float b3 = 5.0f * t * b2 + b1;
        o1[j] = f2bf(b1); o2[j] = f2bf(b2); o3[j] = f2bf(b3);
    }
    short* row = A + (size_t)b * KDIM;
    *reinterpret_cast<short4*>(&row[i])              = make_short4(o1[0], o1[1], o1[2], o1[3]);
    *reinterpret_cast<short4*>(&row[IN_DIM + i])     = make_short4(o2[0], o2[1], o2[2], o2[3]);
    *reinterpret_cast<short4*>(&row[2 * IN_DIM + i]) = make_short4(o3[0], o3[1], o3[2], o3[3]);
}

// -------- prep: Bt [1024][3072] bf16 transpose + bias[o] = sum_i C[i][o][0] --------
__global__ __launch_bounds__(256) void prep_coeffs(const float* __restrict__ C,
                                                   short* __restrict__ Bt,
                                                   float* __restrict__ bias) {
    __shared__ short tile[3][32][33];
    __shared__ float red[8][32];
    const int i0 = blockIdx.x * 32;
    const int o0 = blockIdx.y * 32;
    const int t  = threadIdx.x;
    const int lo = t & 31;
    const int li = t >> 5;   // 0..7
    float part = 0.0f;
#pragma unroll
    for (int r = 0; r < 4; ++r) {
        int i = li + r * 8;
        const float4 c4 = *reinterpret_cast<const float4*>(
            &C[((size_t)(i0 + i) * OUT_DIM + (o0 + lo)) * 4]);
        tile[0][i][lo] = f2bf(c4.y);
        tile[1][i][lo] = f2bf(c4.z);
        tile[2][i][lo] = f2bf(c4.w);
        part += c4.x;
    }
    red[li][lo] = part;
    __syncthreads();
#pragma unroll
    for (int r = 0; r < 4; ++r) {
        int o = (t >> 5) + r * 8;
        int i = t & 31;
#pragma unroll
        for (int d = 0; d < 3; ++d)
            Bt[(size_t)(o0 + o) * KDIM + d * IN_DIM + (i0 + i)] = tile[d][i][o];
    }
    if (t < 32) {
        float s = 0.0f;
#pragma unroll
        for (int k = 0; k < 8; ++k) s += red[k][t];
        atomicAdd(&bias[o0 + t], s);
    }
}

// ---------------- GEMM: out = A * Bt^T + bias ----------------
__global__ __launch_bounds__(512, 2) void gemm_kan(
    const short* __restrict__ A,     // [BATCH][KDIM]
    const short* __restrict__ Bt,    // [OUT_DIM][KDIM]
    const float* __restrict__ bias,  // [OUT_DIM]
    float* __restrict__ out)         // [BATCH][OUT_DIM]
{
    extern __shared__ short lds[];   // 3 * LDS_TILE shorts = 144 KB

    const int tid  = threadIdx.x;
    const int lane = tid & 63;
    const int wid  = tid >> 6;   // 0..7
    const int wm   = wid >> 1;   // 0..3 (M)
    const int wn   = wid & 1;    // 0..1 (N)

    // XCD-aware swizzle (round-2 proven): XCD k -> 4 brow x 8 bcol
    const int bid  = blockIdx.x;          // 0..255
    const int swz  = (bid & 7) * 32 + (bid >> 3);
    const int brow = (swz >> 3) * BM;
    const int bcol = (swz & 7) * BN;

    const int l15 = lane & 15, lh = lane >> 4, l7 = lane & 7;
    const int pc0 = lh ^ l7;            // phys chunk for kk=0
    const int pc1 = pc0 ^ 4;            // kk=1

    // fragment LDS offsets (shorts), swizzled: chunk ^= (row & 7)
    int aoff[4][2], boff[4][2];
#pragma unroll
    for (int mi = 0; mi < 4; ++mi) {
        int r = wm * 64 + mi * 16 + l15;
        aoff[mi][0] = r * 64 + pc0 * 8;
        aoff[mi][1] = r * 64 + pc1 * 8;
    }
#pragma unroll
    for (int ni = 0; ni < 4; ++ni) {
        int r = wn * 64 + ni * 16 + l15;
        boff[ni][0] = 16384 + r * 64 + pc0 * 8;
        boff[ni][1] = 16384 + r * 64 + pc1 * 8;
    }

    // staging geometry: thread tid handles row srow (+s*64), phys chunk tid&7
    const int srow   = tid >> 3;                    // 0..63
    const int schunk = (tid & 7) ^ (srow & 7);      // inverse-swizzled src chunk

#define STAGE_A(KT_TILE, B, S)                                                        \
    __builtin_amdgcn_global_load_lds(                                                 \
        (const __attribute__((address_space(1))) void*)(                              \
            A + (size_t)(brow + (S) * 64 + srow) * KDIM + (KT_TILE) * 64 + schunk * 8), \
        (__attribute__((address_space(3))) void*)(                                    \
            lds + (B) * LDS_TILE + (S) * 4096 + tid * 8), 16, 0, 0)
#define STAGE_B(KT_TILE, B, S)                                                        \
    __builtin_amdgcn_global_load_lds(                                                 \
        (const __attribute__((address_space(1))) void*)(                              \
            Bt + (size_t)(bcol + (S) * 64 + srow) * KDIM + (KT_TILE) * 64 + schunk * 8), \
        (__attribute__((address_space(3))) void*)(                                    \
            lds + (B) * LDS_TILE + 16384 + (S) * 4096 + tid * 8), 16, 0, 0)

// half-tile stage chunks (3 DMA each; 6 per K-tile total, matching vmcnt(6))
#define STAGE_H0(T, B)  do { STAGE_A(T, B, 0); STAGE_A(T, B, 1); STAGE_B(T, B, 0); } while (0)
#define STAGE_H1(T, B)  do { STAGE_A(T, B, 2); STAGE_A(T, B, 3); STAGE_B(T, B, 1); } while (0)

// one 8-MFMA cluster: all mi at (KK, ni = N0, N1)
#define CLUSTER(KK, N0, N1)                                                           \
    do {                                                                              \
        _Pragma("unroll")                                                             \
        for (int mi = 0; mi < 4; ++mi) {                                              \
            acc[mi][N0] = __builtin_amdgcn_mfma_f32_16x16x32_bf16(                    \
                af[mi][KK], bfr[N0][KK], acc[mi][N0], 0, 0, 0);                       \
            acc[mi][N1] = __builtin_amdgcn_mfma_f32_16x16x32_bf16(                    \
                af[mi][KK], bfr[N1][KK], acc[mi][N1], 0, 0, 0);                       \
        }                                                                             \
    } while (0)

#define LGKM0_FENCE()                                                                 \
    do { asm volatile("s_waitcnt lgkmcnt(0)" ::: "memory");                           \
         __builtin_amdgcn_sched_barrier(0); } while (0)

// body T: 4 phases (8 per 2 K-tiles). Each phase: {frag ds_reads | stage
// chunk | bar | lgkm0+SB0 | prio1 | 8 MFMA | prio0 | bar}. vmcnt once at P3.
#define BODY(T)                                                                       \
    do {                                                                              \
        const short* Ab = lds + buf * LDS_TILE;                                       \
        const bool pf = (T) + 2 < NT;                                                 \
        bf16x8 af[4][2], bfr[4][2];                                                   \
        /* ---- P0: kk0, ni 0/1 ---- */                                               \
        _Pragma("unroll")                                                             \
        for (int mi = 0; mi < 4; ++mi)                                                \
            af[mi][0] = *reinterpret_cast<const bf16x8*>(Ab + aoff[mi][0]);           \
        bfr[0][0] = *reinterpret_cast<const bf16x8*>(Ab + boff[0][0]);                \
        bfr[1][0] = *reinterpret_cast<const bf16x8*>(Ab + boff[1][0]);                \
        if (pf) STAGE_H0((T) + 2, sbuf);                                              \
        __builtin_amdgcn_s_barrier();                                                 \
        LGKM0_FENCE();                                                                \
        __builtin_amdgcn_s_setprio(1);                                                \
        CLUSTER(0, 0, 1);                                                             \
        __builtin_amdgcn_s_setprio(0);                                                \
        __builtin_amdgcn_s_barrier();                                                 \
        /* ---- P1: kk0, ni 2/3 ---- */                                               \
        bfr[2][0] = *reinterpret_cast<const bf16x8*>(Ab + boff[2][0]);                \
        bfr[3][0] = *reinterpret_cast<const bf16x8*>(Ab + boff[3][0]);                \
        __builtin_amdgcn_s_barrier();                                                 \
        LGKM0_FENCE();                                                                \
        __builtin_amdgcn_s_setprio(1);                                                \
        CLUSTER(0, 2, 3);                                                             \
        __builtin_amdgcn_s_setprio(0);                                                \
        __builtin_amdgcn_s_barrier();                                                 \
        /* ---- P2: kk1, ni 0/1 ---- */                                               \
        _Pragma("unroll")                                                             \
        for (int mi = 0; mi < 4; ++mi)                                                \
            af[mi][1] = *reinterpret_cast<const bf16x8*>(Ab + aoff[mi][1]);           \
        bfr[0][1] = *reinterpret_cast<const bf16x8*>(Ab + boff[0][1]);                \
        bfr[1][1] = *reinterpret_cast<const bf16x8*>(Ab + boff[1][1]);                \
        if (pf) STAGE_H1((T) + 2, sbuf);                                              \
        __builtin_amdgcn_s_barrier();                                                 \
        LGKM0_FENCE();                                                                \
        __builtin_amdgcn_s_setprio(1);                                                \
        CLUSTER(1, 0, 1);                                                             \
        __builtin_amdgcn_s_setprio(0);                                                \
        __builtin_amdgcn_s_barrier();                                                 \
        /* ---- P3: kk1, ni 2/3 + per-tile counted vmcnt ---- */                      \
        bfr[2][1] = *reinterpret_cast<const bf16x8*>(Ab + boff[2][1]);                \
        bfr[3][1] = *reinterpret_cast<const bf16x8*>(Ab + boff[3][1]);                \
        __builtin_amdgcn_s_barrier();                                                 \
        LGKM0_FENCE();                                                                \
        __builtin_amdgcn_s_setprio(1);                                                \
        CLUSTER(1, 2, 3);                                                             \
        __builtin_amdgcn_s_setprio(0);                                                \
        if (pf) { asm volatile("s_waitcnt vmcnt(6)" ::: "memory"); }                  \
        else    { asm volatile("s_waitcnt vmcnt(0)" ::: "memory"); }                  \
        __builtin_amdgcn_s_barrier();                                                 \
        buf  = (buf  == 2) ? 0 : buf  + 1;                                            \
        sbuf = (sbuf == 2) ? 0 : sbuf + 1;                                            \
    } while (0)

    // prologue: bias -> acc, stage tiles 0 and 1
    f32x4 acc[4][4];
#pragma unroll
    for (int ni = 0; ni < 4; ++ni) {
        float bv = bias[bcol + wn * 64 + ni * 16 + l15];
#pragma unroll
        for (int mi = 0; mi < 4; ++mi)
            acc[mi][ni] = (f32x4){bv, bv, bv, bv};
    }
    STAGE_H0(0, 0); STAGE_H1(0, 0);
    STAGE_H0(1, 1); STAGE_H1(1, 1);
    asm volatile("s_waitcnt vmcnt(6)" ::: "memory");   // tile 0 landed
    __builtin_amdgcn_s_barrier();

    int buf = 0, sbuf = 2;
    for (int t = 0; t < NT; ++t) {
        BODY(t);
    }
#undef BODY
#undef CLUSTER
#undef LGKM0_FENCE
#undef STAGE_H0
#undef STAGE_H1
#undef STAGE_A
#undef STAGE_B

    // epilogue: C/D layout col = lane&15, row = (lane>>4)*4 + reg
#pragma unroll
    for (int mi = 0; mi < 4; ++mi) {
#pragma unroll
        for (int r = 0; r < 4; ++r) {
            int row = brow + wm * 64 + mi * 16 + (lane >> 4) * 4 + r;
            float* orow = out + (size_t)row * OUT_DIM + bcol + wn * 64 + l15;
#pragma unroll
            for (int ni = 0; ni < 4; ++ni)
                orow[ni * 16] = acc[mi][ni][r];
        }
    }
}

extern "C" void kernel_launch(void* const* d_in, const int* in_sizes, int n_in,
                              void* d_out, int out_size, void* d_ws, size_t ws_size,
                              hipStream_t stream) {
    (void)in_sizes; (void)n_in; (void)out_size; (void)ws_size;
    const float* x      = (const float*)d_in[0];
    const float* coeffs = (const float*)d_in[1];
    float* out = (float*)d_out;

    char* ws = (char*)d_ws;
    short* A    = (short*)ws;                                        // 48 MB
    short* Bt   = (short*)(ws + (size_t)BATCH * KDIM * 2);           // 6 MB
    float* bias = (float*)(ws + (size_t)BATCH * KDIM * 2
                              + (size_t)OUT_DIM * KDIM * 2);         // 4 KB

    hipFuncSetAttribute((const void*)gemm_kan,
                        hipFuncAttributeMaxDynamicSharedMemorySize,
                        3 * LDS_TILE * (int)sizeof(short));

    hipMemsetAsync(bias, 0, OUT_DIM * sizeof(float), stream);
    hipLaunchKernelGGL(prep_basis, dim3(BATCH * IN_DIM / 4 / 256), dim3(256), 0, stream,
                       x, A);
    hipLaunchKernelGGL(prep_coeffs, dim3(IN_DIM / 32, OUT_DIM / 32), dim3(256), 0, stream,
                       coeffs, Bt, bias);
    hipLaunchKernelGGL(gemm_kan, dim3((BATCH / BM) * (OUT_DIM / BN)), dim3(512),
                       3 * LDS_TILE * sizeof(short), stream,
                       A, Bt, bias, out);
}

// Round 9
// 76.847 us; speedup vs baseline: 1.1574x; 1.0670x over previous
//
#include <hip/hip_runtime.h>
#include <hip/hip_bf16.h>
#include <cstdint>
#include <cstddef>

// BesselKANLayer: y[b,o] = sum_{i,d} bessel_d(tanh(x[b,i])) * C[i,o,d]
// b0 == 1 folded into bias; GEMM K = 3*1024.
// GEMM: BM=BN=128, BK=64, 256 thr (4 waves 2x2, wave tile 64x64),
// DOUBLE-buffered 64KB LDS -> grid 512 = 2 blocks/CU: cross-block TLP
// covers the per-block vmcnt(0) drain (m103 mechanism, 912 TF) while
// keeping round-2's proven XOR swizzle (conflicts=0) + setprio + XCD map.

#define BATCH   8192
#define IN_DIM  1024
#define OUT_DIM 1024
#define KDIM    3072
#define NT      48            // KDIM/64 K-tiles
#define BM      128
#define BN      128
#define BUF_SH  16384         // shorts per buffer: A 128*64 + B 128*64

typedef __attribute__((ext_vector_type(4))) float f32x4;
typedef __attribute__((ext_vector_type(8))) short bf16x8;

static __device__ __forceinline__ short f2bf(float f) {
    uint32_t u = __float_as_uint(f);
    u += 0x7fffu + ((u >> 16) & 1u);
    return (short)(u >> 16);
}

// ---------------- prep: basis matrix A [8192][3072] bf16 ----------------
__global__ __launch_bounds__(256) void prep_basis(const float* __restrict__ x,
                                                  short* __restrict__ A) {
    int idx = blockIdx.x * 256 + threadIdx.x;
    int b = idx >> 8;
    int i = (idx & 255) << 2;
    const float4 xv = *reinterpret_cast<const float4*>(&x[(size_t)b * IN_DIM + i]);
    float xs[4] = {xv.x, xv.y, xv.z, xv.w};
    short o1[4], o2[4], o3[4];
#pragma unroll
    for (int j = 0; j < 4; ++j) {
        float t  = tanhf(xs[j]);
        float b1 = t + 1.0f;
        float b2 = 3.0f * t * b1 + 1.0f;
        float b3 = 5.0f * t * b2 + b1;
        o1[j] = f2bf(b1); o2[j] = f2bf(b2); o3[j] = f2bf(b3);
    }
    short* row = A + (size_t)b * KDIM;
    *reinterpret_cast<short4*>(&row[i])              = make_short4(o1[0], o1[1], o1[2], o1[3]);
    *reinterpret_cast<short4*>(&row[IN_DIM + i])     = make_short4(o2[0], o2[1], o2[2], o2[3]);
    *reinterpret_cast<short4*>(&row[2 * IN_DIM + i]) = make_short4(o3[0], o3[1], o3[2], o3[3]);
}

// -------- prep: Bt [1024][3072] bf16 transpose + bias[o] = sum_i C[i][o][0] --------
__global__ __launch_bounds__(256) void prep_coeffs(const float* __restrict__ C,
                                                   short* __restrict__ Bt,
                                                   float* __restrict__ bias) {
    __shared__ short tile[3][32][33];
    __shared__ float red[8][32];
    const int i0 = blockIdx.x * 32;
    const int o0 = blockIdx.y * 32;
    const int t  = threadIdx.x;
    const int lo = t & 31;
    const int li = t >> 5;   // 0..7
    float part = 0.0f;
#pragma unroll
    for (int r = 0; r < 4; ++r) {
        int i = li + r * 8;
        const float4 c4 = *reinterpret_cast<const float4*>(
            &C[((size_t)(i0 + i) * OUT_DIM + (o0 + lo)) * 4]);
        tile[0][i][lo] = f2bf(c4.y);
        tile[1][i][lo] = f2bf(c4.z);
        tile[2][i][lo] = f2bf(c4.w);
        part += c4.x;
    }
    red[li][lo] = part;
    __syncthreads();
#pragma unroll
    for (int r = 0; r < 4; ++r) {
        int o = (t >> 5) + r * 8;
        int i = t & 31;
#pragma unroll
        for (int d = 0; d < 3; ++d)
            Bt[(size_t)(o0 + o) * KDIM + d * IN_DIM + (i0 + i)] = tile[d][i][o];
    }
    if (t < 32) {
        float s = 0.0f;
#pragma unroll
        for (int k = 0; k < 8; ++k) s += red[k][t];
        atomicAdd(&bias[o0 + t], s);
    }
}

// ---------------- GEMM: out = A * Bt^T + bias ----------------
__global__ __launch_bounds__(256, 2) void gemm_kan(
    const short* __restrict__ A,     // [BATCH][KDIM]
    const short* __restrict__ Bt,    // [OUT_DIM][KDIM]
    const float* __restrict__ bias,  // [OUT_DIM]
    float* __restrict__ out)         // [BATCH][OUT_DIM]
{
    extern __shared__ short lds[];   // 2 * BUF_SH shorts = 64 KB

    const int tid  = threadIdx.x;
    const int lane = tid & 63;
    const int wid  = tid >> 6;   // 0..3
    const int wm   = wid >> 1;   // 0..1 (M)
    const int wn   = wid & 1;    // 0..1 (N)

    // XCD map: grid 512 = 64 brow x 8 bcol; XCD k -> 16 brow x 4 bcol
    // (B slice 3MB < 4MB L2). Bijective: xcd 0..7, j 0..63.
    const int bid  = blockIdx.x;
    const int xcd  = bid & 7;
    const int j    = bid >> 3;
    const int brow = ((xcd >> 1) * 16 + (j >> 2)) * BM;
    const int bcol = ((xcd & 1) * 4 + (j & 3)) * BN;

    const int l15 = lane & 15, lh = lane >> 4, l7 = lane & 7;
    const int pc0 = lh ^ l7;            // phys chunk for kk=0 (swizzled)
    const int pc1 = pc0 ^ 4;            // kk=1

    // fragment LDS offsets (shorts), swizzle: chunk ^= (row & 7)
    int aoff[4][2], boff[4][2];
#pragma unroll
    for (int mi = 0; mi < 4; ++mi) {
        int r = wm * 64 + mi * 16 + l15;
        aoff[mi][0] = r * 64 + pc0 * 8;
        aoff[mi][1] = r * 64 + pc1 * 8;
    }
#pragma unroll
    for (int ni = 0; ni < 4; ++ni) {
        int r = wn * 64 + ni * 16 + l15;
        boff[ni][0] = 8192 + r * 64 + pc0 * 8;
        boff[ni][1] = 8192 + r * 64 + pc1 * 8;
    }

    // staging: 256 thr x 16B = 4KB/instr = 32 rows; A 4 instr + B 4 instr
    const int srow   = tid >> 3;                    // 0..31
    const int schunk = (tid & 7) ^ (srow & 7);      // inverse-swizzled src chunk

#define STAGE(KT_TILE, B)                                                             \
    do {                                                                              \
        const int kt_ = (KT_TILE) * 64;                                               \
        short* lbase_ = lds + (B) * BUF_SH;                                           \
        _Pragma("unroll")                                                             \
        for (int s_ = 0; s_ < 4; ++s_) {                                              \
            __builtin_amdgcn_global_load_lds(                                         \
                (const __attribute__((address_space(1))) void*)(                      \
                    A + (size_t)(brow + s_ * 32 + srow) * KDIM + kt_ + schunk * 8),   \
                (__attribute__((address_space(3))) void*)(                            \
                    lbase_ + s_ * 2048 + tid * 8), 16, 0, 0);                         \
        }                                                                             \
        _Pragma("unroll")                                                             \
        for (int s_ = 0; s_ < 4; ++s_) {                                              \
            __builtin_amdgcn_global_load_lds(                                         \
                (const __attribute__((address_space(1))) void*)(                      \
                    Bt + (size_t)(bcol + s_ * 32 + srow) * KDIM + kt_ + schunk * 8),  \
                (__attribute__((address_space(3))) void*)(                            \
                    lbase_ + 8192 + s_ * 2048 + tid * 8), 16, 0, 0);                  \
        }                                                                             \
    } while (0)

    // prologue
    f32x4 acc[4][4];
#pragma unroll
    for (int ni = 0; ni < 4; ++ni) {
        float bv = bias[bcol + wn * 64 + ni * 16 + l15];
#pragma unroll
        for (int mi = 0; mi < 4; ++mi)
            acc[mi][ni] = (f32x4){bv, bv, bv, bv};
    }
    STAGE(0, 0);
    __syncthreads();                   // drains vmcnt -> tile 0 in LDS

    for (int t = 0; t < NT; ++t) {
        const int p = t & 1;
        if (t + 1 < NT) STAGE(t + 1, p ^ 1);    // prefetch next tile

        const short* Ab = lds + p * BUF_SH;
        bf16x8 af[4][2], bfr[4][2];
#pragma unroll
        for (int mi = 0; mi < 4; ++mi) {
            af[mi][0] = *reinterpret_cast<const bf16x8*>(Ab + aoff[mi][0]);
            af[mi][1] = *reinterpret_cast<const bf16x8*>(Ab + aoff[mi][1]);
        }
#pragma unroll
        for (int ni = 0; ni < 4; ++ni) {
            bfr[ni][0] = *reinterpret_cast<const bf16x8*>(Ab + boff[ni][0]);
            bfr[ni][1] = *reinterpret_cast<const bf16x8*>(Ab + boff[ni][1]);
        }
        __builtin_amdgcn_s_setprio(1);
#pragma unroll
        for (int kk = 0; kk < 2; ++kk)
#pragma unroll
            for (int mi = 0; mi < 4; ++mi)
#pragma unroll
                for (int ni = 0; ni < 4; ++ni)
                    acc[mi][ni] = __builtin_amdgcn_mfma_f32_16x16x32_bf16(
                        af[mi][kk], bfr[ni][kk], acc[mi][ni], 0, 0, 0);
        __builtin_amdgcn_s_setprio(0);

        if (t + 1 < NT) __syncthreads();   // vmcnt(0)+barrier: tile t+1 ready;
                                           // drain covered by co-resident block
    }
#undef STAGE

    // epilogue: C/D layout col = lane&15, row = (lane>>4)*4 + reg
#pragma unroll
    for (int mi = 0; mi < 4; ++mi) {
#pragma unroll
        for (int r = 0; r < 4; ++r) {
            int row = brow + wm * 64 + mi * 16 + (lane >> 4) * 4 + r;
            float* orow = out + (size_t)row * OUT_DIM + bcol + wn * 64 + l15;
#pragma unroll
            for (int ni = 0; ni < 4; ++ni)
                orow[ni * 16] = acc[mi][ni][r];
        }
    }
}

extern "C" void kernel_launch(void* const* d_in, const int* in_sizes, int n_in,
                              void* d_out, int out_size, void* d_ws, size_t ws_size,
                              hipStream_t stream) {
    (void)in_sizes; (void)n_in; (void)out_size; (void)ws_size;
    const float* x      = (const float*)d_in[0];
    const float* coeffs = (const float*)d_in[1];
    float* out = (float*)d_out;

    char* ws = (char*)d_ws;
    short* A    = (short*)ws;                                        // 48 MB
    short* Bt   = (short*)(ws + (size_t)BATCH * KDIM * 2);           // 6 MB
    float* bias = (float*)(ws + (size_t)BATCH * KDIM * 2
                              + (size_t)OUT_DIM * KDIM * 2);         // 4 KB

    hipFuncSetAttribute((const void*)gemm_kan,
                        hipFuncAttributeMaxDynamicSharedMemorySize,
                        2 * BUF_SH * (int)sizeof(short));

    hipMemsetAsync(bias, 0, OUT_DIM * sizeof(float), stream);
    hipLaunchKernelGGL(prep_basis, dim3(BATCH * IN_DIM / 4 / 256), dim3(256), 0, stream,
                       x, A);
    hipLaunchKernelGGL(prep_coeffs, dim3(IN_DIM / 32, OUT_DIM / 32), dim3(256), 0, stream,
                       coeffs, Bt, bias);
    hipLaunchKernelGGL(gemm_kan, dim3((BATCH / BM) * (OUT_DIM / BN)), dim3(256),
                       2 * BUF_SH * sizeof(short), stream,
                       A, Bt, bias, out);
}